// Round 8
// baseline (8511.530 us; speedup 1.0000x reference)
//
#include <hip/hip_runtime.h>
#include <math.h>

#define CC 1024
#define LL 2048
#define NWG 256
#define NT 256

typedef float f4 __attribute__((ext_vector_type(4)));
typedef unsigned u4 __attribute__((ext_vector_type(4)));

// ws word layout:
// [0..8191]      packet buffers: 2 parities x 4 arrays x 1024 words     [memset 0]
//                array w holds producer g's packet at w*1024 + 4*g:
//                (h0[4g+w], h1[4g+w], pad, tag)  -- tag = tau+1, exact match
// [8192..16383]  gbar arrival epochs (256 x 32 words, 128B lines)       [memset 0]
// [16384]        gbar release epoch                                     [memset 0]
// [16448..18495] logits[2048]
// [18496..19519] av[1024]
#define PKT_PAR 4096
#define PKT_ARR 1024
#define WS_FLAGS 8192
#define WS_REL 16384
#define WS_LOGITS 16448
#define WS_AV (WS_LOGITS + LL)
#define WS_MEMSET_BYTES ((WS_REL + 64) * 4)

__device__ __forceinline__ float aload(const float* p) {
  return __hip_atomic_load(p, __ATOMIC_RELAXED, __HIP_MEMORY_SCOPE_AGENT);
}
__device__ __forceinline__ void astore(float* p, float v) {
  __hip_atomic_store(p, v, __ATOMIC_RELAXED, __HIP_MEMORY_SCOPE_AGENT);
}
__device__ __forceinline__ float sigm(float x) { return 1.0f / (1.0f + __expf(-x)); }
__device__ __forceinline__ float tanh_(float x) { return 2.0f / (1.0f + __expf(-2.0f * x)) - 1.0f; }

__device__ __forceinline__ float dot4(f4 a, f4 b) {
  return fmaf(a.x, b.x, fmaf(a.y, b.y, fmaf(a.z, b.z, a.w * b.w)));
}

// L2-bypass 16B ops (coherence at L3)
__device__ __forceinline__ u4 ld16v(const unsigned* p) {  // issue only, no wait
  u4 r;
  asm volatile("global_load_dwordx4 %0, %1, off sc0 sc1" : "=v"(r) : "v"(p) : "memory");
  return r;
}
__device__ __forceinline__ void vm0() { asm volatile("s_waitcnt vmcnt(0)" ::: "memory"); }
__device__ __forceinline__ void st16u(unsigned* p, u4 v) {
  asm volatile("global_store_dwordx4 %0, %1, off sc0 sc1" ::"v"(p), "v"(v) : "memory");
}

// prologue-only arrival-slot barrier (relaxed spins + one acquire)
__device__ __forceinline__ void gbar(unsigned* ws_u, unsigned epoch) {
  __syncthreads();
  if (blockIdx.x == 0) {
    const int i = threadIdx.x;
    if (i > 0 && i < NWG) {
      unsigned* slot = ws_u + WS_FLAGS + i * 32;
      while (__hip_atomic_load(slot, __ATOMIC_RELAXED, __HIP_MEMORY_SCOPE_AGENT) < epoch) {
      }
      (void)__hip_atomic_load(slot, __ATOMIC_ACQUIRE, __HIP_MEMORY_SCOPE_AGENT);
    }
    __syncthreads();
    if (i == 0)
      __hip_atomic_store(ws_u + WS_REL, epoch, __ATOMIC_RELEASE, __HIP_MEMORY_SCOPE_AGENT);
    __syncthreads();
  } else {
    if (threadIdx.x == 0) {
      __hip_atomic_store(ws_u + WS_FLAGS + blockIdx.x * 32, epoch, __ATOMIC_RELEASE,
                         __HIP_MEMORY_SCOPE_AGENT);
      unsigned* rel = ws_u + WS_REL;
      while (__hip_atomic_load(rel, __ATOMIC_RELAXED, __HIP_MEMORY_SCOPE_AGENT) < epoch) {
      }
      (void)__hip_atomic_load(rel, __ATOMIC_ACQUIRE, __HIP_MEMORY_SCOPE_AGENT);
    }
    __syncthreads();
  }
}

__global__ __launch_bounds__(NT, 1) void decoder_kernel(
    const float* __restrict__ x, const float* __restrict__ attn_w,
    const float* __restrict__ w_ih0, const float* __restrict__ w_hh0,
    const float* __restrict__ b_ih0, const float* __restrict__ b_hh0,
    const float* __restrict__ w_ih1, const float* __restrict__ w_hh1,
    const float* __restrict__ b_ih1, const float* __restrict__ b_hh1,
    float* __restrict__ out, float* __restrict__ ws) {
  const int g = blockIdx.x;
  const int tid = threadIdx.x;
  const int lane = tid & 63;
  const int w = tid >> 6;
  const int eg = 4 * g + w;  // element owned by this wave

  unsigned* ws_u = (unsigned*)ws;

  extern __shared__ float wlds[];  // 36 rows x 1024 f32 = 144 KB
  __shared__ __align__(16) float h0s[CC];
  __shared__ __align__(16) float h1s[CC];
  __shared__ float cgi0[12], cbh0[12], cbh1[12], cbi1[12];
  __shared__ float red[NT];

  // ---------- P0: logits[t] = dot(w2, x[t]) ----------
  {
    const float* w2 = attn_w + CC;
#pragma unroll
    for (int s = 0; s < 2; ++s) {
      int t = 8 * g + 2 * w + s;
      const float* xr = x + (size_t)t * CC;
      float p = 0.f;
#pragma unroll
      for (int k = 0; k < 4; ++k) {
        f4 xa = *(const f4*)(xr + 256 * k + 4 * lane);
        f4 wa = *(const f4*)(w2 + 256 * k + 4 * lane);
        p += dot4(xa, wa);
      }
#pragma unroll
      for (int off = 32; off; off >>= 1) p += __shfl_xor(p, off, 64);
      if (lane == 0) astore(ws + WS_LOGITS + t, p);
    }
  }
  gbar(ws_u, 1);

  // ---------- P1: softmax over L, av columns [4g,4g+4) ----------
  {
    float myl[8];
#pragma unroll
    for (int s = 0; s < 8; ++s) myl[s] = aload(ws + WS_LOGITS + tid + 256 * s);
    float lm = myl[0];
#pragma unroll
    for (int s = 1; s < 8; ++s) lm = fmaxf(lm, myl[s]);
    red[tid] = lm;
    __syncthreads();
    for (int stp = 128; stp; stp >>= 1) {
      if (tid < stp) red[tid] = fmaxf(red[tid], red[tid + stp]);
      __syncthreads();
    }
    float m = red[0];
    __syncthreads();
    float myw[8];
    float ls = 0.f;
#pragma unroll
    for (int s = 0; s < 8; ++s) {
      myw[s] = __expf(myl[s] - m);
      ls += myw[s];
    }
    red[tid] = ls;
    __syncthreads();
    for (int stp = 128; stp; stp >>= 1) {
      if (tid < stp) red[tid] += red[tid + stp];
      __syncthreads();
    }
    float invZ = 1.0f / red[0];
    __syncthreads();
    float acc[4] = {0.f, 0.f, 0.f, 0.f};
#pragma unroll
    for (int s = 0; s < 8; ++s) {
      int t = tid + 256 * s;
      f4 xa = *(const f4*)(x + (size_t)t * CC + 4 * g);
      acc[0] = fmaf(myw[s], xa.x, acc[0]);
      acc[1] = fmaf(myw[s], xa.y, acc[1]);
      acc[2] = fmaf(myw[s], xa.z, acc[2]);
      acc[3] = fmaf(myw[s], xa.w, acc[3]);
    }
    for (int i = 0; i < 4; ++i) {
      red[tid] = acc[i];
      __syncthreads();
      for (int stp = 128; stp; stp >>= 1) {
        if (tid < stp) red[tid] += red[tid + stp];
        __syncthreads();
      }
      if (tid == 0) astore(ws + WS_AV + 4 * g + i, red[0] * invZ);
      __syncthreads();
    }
  }
  gbar(ws_u, 2);

  // ---------- P2: gi0 = W_ih0 . av + b_ih0 (this WG's 12 rows); biases ----------
#pragma unroll
  for (int i = 0; i < 4; ++i) h0s[4 * tid + i] = aload(ws + WS_AV + 4 * tid + i);
  __syncthreads();
  {
    f4 hc[4];
#pragma unroll
    for (int k = 0; k < 4; ++k) hc[k] = *(const f4*)&h0s[256 * k + 4 * lane];
#pragma unroll
    for (int jj = 0; jj < 3; ++jj) {
      int j = 3 * w + jj;
      int gate = j >> 2, e = j & 3;
      int row = gate * CC + 4 * g + e;
      const float* wr = w_ih0 + (size_t)row * CC;
      float p = 0.f;
#pragma unroll
      for (int k = 0; k < 4; ++k) p += dot4(*(const f4*)(wr + 256 * k + 4 * lane), hc[k]);
#pragma unroll
      for (int off = 32; off; off >>= 1) p += __shfl_xor(p, off, 64);
      if (lane == 0) cgi0[j] = p + b_ih0[row];
    }
  }
  if (tid < 12) {
    int gate = tid >> 2, e = tid & 3;
    int row = gate * CC + 4 * g + e;
    cbh0[tid] = b_hh0[row];
    cbh1[tid] = b_hh1[row];
    cbi1[tid] = b_ih1[row];
  }

  // ---------- weights -> LDS: wave w's 9 rows at wlds[(w*9 + mat*3 + G)*1024] ----
  // mat 0 = W_hh0 (x h0), mat 1 = W_hh1 (x h1), mat 2 = W_ih1 (x h0); row = G*CC+eg
#pragma unroll
  for (int j = 0; j < 36; ++j) {
    int ww = j / 9, r = j % 9, mat = r / 3, G = r % 3;
    const float* src = (mat == 0 ? w_hh0 : (mat == 1 ? w_hh1 : w_ih1)) +
                       ((size_t)(G * CC + 4 * g + ww) << 10);
    *(f4*)&wlds[j * 1024 + 4 * tid] = *(const f4*)(src + 4 * tid);
  }
  // zero h replicas
#pragma unroll
  for (int i = 0; i < 4; ++i) {
    h0s[4 * tid + i] = 0.f;
    h1s[4 * tid + i] = 0.f;
  }
  __syncthreads();

  // ---------- skewed recurrence: tick tau computes h0[tau] and h1[tau-1] ----------
  float h0last = 0.f;
  unsigned* pkt0 = ws_u;            // parity 0
  unsigned* pkt1 = ws_u + PKT_PAR;  // parity 1
  u4 qa, qb, qc, qd;                // pend packet loads for next tick
  const float* wr9 = wlds + (w * 9) * 1024;

  for (int tau = 0; tau <= LL; ++tau) {
    // (1) poll producer tid's 4 self-validating packets (pend-first; exact tag)
    if (tau > 0) {
      const unsigned ut = (unsigned)tau;
      unsigned* base = (tau & 1) ? pkt1 : pkt0;
      const unsigned* pA = base + 0 * PKT_ARR + 4 * tid;
      const unsigned* pB = base + 1 * PKT_ARR + 4 * tid;
      const unsigned* pC = base + 2 * PKT_ARR + 4 * tid;
      const unsigned* pD = base + 3 * PKT_ARR + 4 * tid;
      vm0();  // pend (issued last tick) arrived
      while (qa.w != ut || qb.w != ut || qc.w != ut || qd.w != ut) {
        qa = ld16v(pA);
        qb = ld16v(pB);
        qc = ld16v(pC);
        qd = ld16v(pD);
        vm0();
      }
      f4 v0, v1;
      v0.x = __uint_as_float(qa.x);
      v0.y = __uint_as_float(qb.x);
      v0.z = __uint_as_float(qc.x);
      v0.w = __uint_as_float(qd.x);
      v1.x = __uint_as_float(qa.y);
      v1.y = __uint_as_float(qb.y);
      v1.z = __uint_as_float(qc.y);
      v1.w = __uint_as_float(qd.y);
      *(f4*)&h0s[4 * tid] = v0;
      *(f4*)&h1s[4 * tid] = v1;
    }
    __syncthreads();
    // (2) 9 dots from LDS weights (3 gates x 3 matrices for element eg)
    f4 hc0[4], hc1[4];
#pragma unroll
    for (int k = 0; k < 4; ++k) {
      hc0[k] = *(const f4*)&h0s[256 * k + 4 * lane];
      hc1[k] = *(const f4*)&h1s[256 * k + 4 * lane];
    }
    float h0prev = h0s[eg];
    float h1prev = h1s[eg];
    float p[9];
#pragma unroll
    for (int G = 0; G < 3; ++G) {
      float pa = 0.f, pb = 0.f, pc = 0.f;
#pragma unroll
      for (int k = 0; k < 4; ++k) {
        int off = 256 * k + 4 * lane;
        pa += dot4(*(const f4*)&wr9[(0 * 3 + G) * 1024 + off], hc0[k]);
        pb += dot4(*(const f4*)&wr9[(1 * 3 + G) * 1024 + off], hc1[k]);
        pc += dot4(*(const f4*)&wr9[(2 * 3 + G) * 1024 + off], hc0[k]);
      }
      p[G] = pa;
      p[3 + G] = pb;
      p[6 + G] = pc;
    }
#pragma unroll
    for (int off = 32; off; off >>= 1) {
#pragma unroll
      for (int i = 0; i < 9; ++i) p[i] += __shfl_xor(p[i], off, 64);
    }
    // (3) elementwise update, wave-local (element eg)
    float r0 = sigm(cgi0[w] + p[0] + cbh0[w]);
    float z0 = sigm(cgi0[4 + w] + p[1] + cbh0[4 + w]);
    float n0 = tanh_(cgi0[8 + w] + r0 * (p[2] + cbh0[8 + w]));
    float h0new = (1.f - z0) * n0 + z0 * h0prev;

    float r1 = sigm(p[6] + cbi1[w] + p[3] + cbh1[w]);
    float z1 = sigm(p[7] + cbi1[4 + w] + p[4] + cbh1[4 + w]);
    float n1 = tanh_(p[8] + cbi1[8 + w] + r1 * (p[5] + cbh1[8 + w]));
    float h1new = (1.f - z1) * n1 + z1 * h1prev;

    // (4) publish one packet per wave (single store, tag fused); write out
    if (lane == 0) {
      if (tau < LL) {
        u4 pk;
        pk.x = __float_as_uint(h0new);
        pk.y = __float_as_uint((tau > 0) ? h1new : 0.f);
        pk.z = 0u;
        pk.w = (unsigned)(tau + 1);
        unsigned* dst = (((tau + 1) & 1) ? pkt1 : pkt0) + w * PKT_ARR + 4 * g;
        st16u(dst, pk);
      }
      if (tau > 0) out[(size_t)(tau - 1) * CC + eg] = h1new;
      if (tau == LL) {
        out[(size_t)LL * CC + eg] = h0last;
        out[(size_t)LL * CC + CC + eg] = h1new;
      }
    }
    if (tau == LL - 1) h0last = h0new;
    // (5) pend prefetch of next tick's packets (stale reads are re-polled)
    if (tau < LL) {
      unsigned* nb = ((tau + 1) & 1) ? pkt1 : pkt0;
      qa = ld16v(nb + 0 * PKT_ARR + 4 * tid);
      qb = ld16v(nb + 1 * PKT_ARR + 4 * tid);
      qc = ld16v(nb + 2 * PKT_ARR + 4 * tid);
      qd = ld16v(nb + 3 * PKT_ARR + 4 * tid);
    }
    __syncthreads();  // protect h0s/h1s from next tick's overwrite
  }
}

extern "C" void kernel_launch(void* const* d_in, const int* in_sizes, int n_in,
                              void* d_out, int out_size, void* d_ws, size_t ws_size,
                              hipStream_t stream) {
  const float* x = (const float*)d_in[0];
  const float* attn_w = (const float*)d_in[1];
  const float* w_ih0 = (const float*)d_in[3];
  const float* w_hh0 = (const float*)d_in[4];
  const float* b_ih0 = (const float*)d_in[5];
  const float* b_hh0 = (const float*)d_in[6];
  const float* w_ih1 = (const float*)d_in[7];
  const float* w_hh1 = (const float*)d_in[8];
  const float* b_ih1 = (const float*)d_in[9];
  const float* b_hh1 = (const float*)d_in[10];
  float* out = (float*)d_out;
  float* ws = (float*)d_ws;

  static int attr_set = 0;
  if (!attr_set) {
    hipFuncSetAttribute((const void*)decoder_kernel,
                        hipFuncAttributeMaxDynamicSharedMemorySize, 36 * 1024 * 4);
    attr_set = 1;
  }

  // zero packet tags + gbar flags every call (tags start at 1 => 0 invalid; no ABA)
  hipMemsetAsync(d_ws, 0, WS_MEMSET_BYTES, stream);

  void* args[] = {&x,     &attn_w, &w_ih0, &w_hh0, &b_ih0, &b_hh0,
                  &w_ih1, &w_hh1,  &b_ih1, &b_hh1, &out,   &ws};
  hipLaunchCooperativeKernel((void*)decoder_kernel, dim3(NWG), dim3(NT), args,
                             36 * 1024 * 4, stream);
}

// Round 9
// 7336.195 us; speedup vs baseline: 1.1602x; 1.1602x over previous
//
#include <hip/hip_runtime.h>
#include <math.h>

#define CC 1024
#define LL 2048
#define NWG 256
#define NT 256

typedef float f4 __attribute__((ext_vector_type(4)));
typedef unsigned u4 __attribute__((ext_vector_type(4)));
typedef unsigned u2v __attribute__((ext_vector_type(2)));

// ws word layout:
// [0 .. 4095]     h0 packets: 2 parities x 1024 elems x 2 words (val, tag) [memset 0]
// [4096 .. 8191]  h1 packets: same layout                                  [memset 0]
// [8192..16383]   gbar arrival epochs (256 x 32 words, 128B lines)         [memset 0]
// [16384]         gbar release epoch                                       [memset 0]
// [16448..18495]  logits[2048]
// [18496..19519]  av[1024]
// tag = tau+1 written at tick tau, parity (tau+1)&1; exact-match poll.
#define H1_BASE 4096
#define PKT_PAR 2048
#define WS_FLAGS 8192
#define WS_REL 16384
#define WS_LOGITS 16448
#define WS_AV (WS_LOGITS + LL)
#define WS_MEMSET_BYTES ((WS_REL + 64) * 4)

__device__ __forceinline__ float aload(const float* p) {
  return __hip_atomic_load(p, __ATOMIC_RELAXED, __HIP_MEMORY_SCOPE_AGENT);
}
__device__ __forceinline__ void astore(float* p, float v) {
  __hip_atomic_store(p, v, __ATOMIC_RELAXED, __HIP_MEMORY_SCOPE_AGENT);
}
__device__ __forceinline__ float sigm(float x) { return 1.0f / (1.0f + __expf(-x)); }
__device__ __forceinline__ float tanh_(float x) { return 2.0f / (1.0f + __expf(-2.0f * x)) - 1.0f; }
__device__ __forceinline__ float dot4(f4 a, f4 b) {
  return fmaf(a.x, b.x, fmaf(a.y, b.y, fmaf(a.z, b.z, a.w * b.w)));
}

// L2-bypass ops (coherence at L3)
__device__ __forceinline__ u4 ld16v(const unsigned* p) {  // issue only, no wait
  u4 r;
  asm volatile("global_load_dwordx4 %0, %1, off sc0 sc1" : "=v"(r) : "v"(p) : "memory");
  return r;
}
__device__ __forceinline__ void vm0() { asm volatile("s_waitcnt vmcnt(0)" ::: "memory"); }
__device__ __forceinline__ void st8u(unsigned* p, u2v v) {
  asm volatile("global_store_dwordx2 %0, %1, off sc0 sc1" ::"v"(p), "v"(v) : "memory");
}

// prologue-only arrival-slot barrier (relaxed spins + one acquire)
__device__ __forceinline__ void gbar(unsigned* ws_u, unsigned epoch) {
  __syncthreads();
  if (blockIdx.x == 0) {
    const int i = threadIdx.x;
    if (i > 0 && i < NWG) {
      unsigned* slot = ws_u + WS_FLAGS + i * 32;
      while (__hip_atomic_load(slot, __ATOMIC_RELAXED, __HIP_MEMORY_SCOPE_AGENT) < epoch) {
      }
      (void)__hip_atomic_load(slot, __ATOMIC_ACQUIRE, __HIP_MEMORY_SCOPE_AGENT);
    }
    __syncthreads();
    if (i == 0)
      __hip_atomic_store(ws_u + WS_REL, epoch, __ATOMIC_RELEASE, __HIP_MEMORY_SCOPE_AGENT);
    __syncthreads();
  } else {
    if (threadIdx.x == 0) {
      __hip_atomic_store(ws_u + WS_FLAGS + blockIdx.x * 32, epoch, __ATOMIC_RELEASE,
                         __HIP_MEMORY_SCOPE_AGENT);
      unsigned* rel = ws_u + WS_REL;
      while (__hip_atomic_load(rel, __ATOMIC_RELAXED, __HIP_MEMORY_SCOPE_AGENT) < epoch) {
      }
      (void)__hip_atomic_load(rel, __ATOMIC_ACQUIRE, __HIP_MEMORY_SCOPE_AGENT);
    }
    __syncthreads();
  }
}

#define PIN12                                                                        \
  asm volatile("" : "+v"(Wa[0]), "+v"(Wa[1]), "+v"(Wa[2]), "+v"(Wa[3]), "+v"(Wa[4]), \
                    "+v"(Wa[5]), "+v"(Wa[6]), "+v"(Wa[7]), "+v"(Wa[8]), "+v"(Wa[9]), \
                    "+v"(Wa[10]), "+v"(Wa[11]))

__global__ __launch_bounds__(NT, 1) void decoder_kernel(
    const float* __restrict__ x, const float* __restrict__ attn_w,
    const float* __restrict__ w_ih0, const float* __restrict__ w_hh0,
    const float* __restrict__ b_ih0, const float* __restrict__ b_hh0,
    const float* __restrict__ w_ih1, const float* __restrict__ w_hh1,
    const float* __restrict__ b_ih1, const float* __restrict__ b_hh1,
    float* __restrict__ out, float* __restrict__ ws) {
  const int g = blockIdx.x;
  const int tid = threadIdx.x;
  const int lane = tid & 63;
  const int w = tid >> 6;
  const int eg = 4 * g + w;  // element owned by this wave

  unsigned* ws_u = (unsigned*)ws;

  extern __shared__ float wcb[];  // 24 rows x 1024 f32 = 96 KB: wave w rows at (w*6+idx)
                                  // idx 0..2 = W_ih1 gates (C), 3..5 = W_hh1 gates (B)
  __shared__ __align__(16) float h0s[CC];
  __shared__ __align__(16) float h1s[CC];
  __shared__ float cgi0[12], cbh0[12], cbh1[12], cbi1[12];
  __shared__ float red[NT];

  // ---------- P0: logits[t] = dot(w2, x[t]) ----------
  {
    const float* w2 = attn_w + CC;
#pragma unroll
    for (int s = 0; s < 2; ++s) {
      int t = 8 * g + 2 * w + s;
      const float* xr = x + (size_t)t * CC;
      float p = 0.f;
#pragma unroll
      for (int k = 0; k < 4; ++k) {
        f4 xa = *(const f4*)(xr + 256 * k + 4 * lane);
        f4 wa = *(const f4*)(w2 + 256 * k + 4 * lane);
        p += dot4(xa, wa);
      }
#pragma unroll
      for (int off = 32; off; off >>= 1) p += __shfl_xor(p, off, 64);
      if (lane == 0) astore(ws + WS_LOGITS + t, p);
    }
  }
  gbar(ws_u, 1);

  // ---------- P1: softmax over L, av columns [4g,4g+4) ----------
  {
    float myl[8];
#pragma unroll
    for (int s = 0; s < 8; ++s) myl[s] = aload(ws + WS_LOGITS + tid + 256 * s);
    float lm = myl[0];
#pragma unroll
    for (int s = 1; s < 8; ++s) lm = fmaxf(lm, myl[s]);
    red[tid] = lm;
    __syncthreads();
    for (int stp = 128; stp; stp >>= 1) {
      if (tid < stp) red[tid] = fmaxf(red[tid], red[tid + stp]);
      __syncthreads();
    }
    float m = red[0];
    __syncthreads();
    float myw[8];
    float ls = 0.f;
#pragma unroll
    for (int s = 0; s < 8; ++s) {
      myw[s] = __expf(myl[s] - m);
      ls += myw[s];
    }
    red[tid] = ls;
    __syncthreads();
    for (int stp = 128; stp; stp >>= 1) {
      if (tid < stp) red[tid] += red[tid + stp];
      __syncthreads();
    }
    float invZ = 1.0f / red[0];
    __syncthreads();
    float acc[4] = {0.f, 0.f, 0.f, 0.f};
#pragma unroll
    for (int s = 0; s < 8; ++s) {
      int t = tid + 256 * s;
      f4 xa = *(const f4*)(x + (size_t)t * CC + 4 * g);
      acc[0] = fmaf(myw[s], xa.x, acc[0]);
      acc[1] = fmaf(myw[s], xa.y, acc[1]);
      acc[2] = fmaf(myw[s], xa.z, acc[2]);
      acc[3] = fmaf(myw[s], xa.w, acc[3]);
    }
    for (int i = 0; i < 4; ++i) {
      red[tid] = acc[i];
      __syncthreads();
      for (int stp = 128; stp; stp >>= 1) {
        if (tid < stp) red[tid] += red[tid + stp];
        __syncthreads();
      }
      if (tid == 0) astore(ws + WS_AV + 4 * g + i, red[0] * invZ);
      __syncthreads();
    }
  }
  gbar(ws_u, 2);

  // ---------- P2: gi0 = W_ih0 . av + b_ih0 (this WG's 12 rows); biases ----------
#pragma unroll
  for (int i = 0; i < 4; ++i) h0s[4 * tid + i] = aload(ws + WS_AV + 4 * tid + i);
  __syncthreads();
  {
    f4 hc[4];
#pragma unroll
    for (int k = 0; k < 4; ++k) hc[k] = *(const f4*)&h0s[256 * k + 4 * lane];
#pragma unroll
    for (int jj = 0; jj < 3; ++jj) {
      int j = 3 * w + jj;
      int gate = j >> 2, e = j & 3;
      int row = gate * CC + 4 * g + e;
      const float* wr = w_ih0 + (size_t)row * CC;
      float p = 0.f;
#pragma unroll
      for (int k = 0; k < 4; ++k) p += dot4(*(const f4*)(wr + 256 * k + 4 * lane), hc[k]);
#pragma unroll
      for (int off = 32; off; off >>= 1) p += __shfl_xor(p, off, 64);
      if (lane == 0) cgi0[j] = p + b_ih0[row];
    }
  }
  if (tid < 12) {
    int gate = tid >> 2, e = tid & 3;
    int row = gate * CC + 4 * g + e;
    cbh0[tid] = b_hh0[row];
    cbh1[tid] = b_hh1[row];
    cbi1[tid] = b_ih1[row];
  }

  // ---------- A-weights (W_hh0, 3 gate rows of eg) -> VGPRs (48 regs, pinned) ----------
  f4 Wa[12];
#pragma unroll
  for (int G = 0; G < 3; ++G) {
    const float* wr = w_hh0 + ((size_t)(G * CC + eg) << 10);
#pragma unroll
    for (int k = 0; k < 4; ++k) Wa[G * 4 + k] = *(const f4*)(wr + 256 * k + 4 * lane);
  }

  // ---------- B/C weights -> LDS ----------
#pragma unroll
  for (int j = 0; j < 24; ++j) {
    int ww = j / 6, r = j % 6;
    int G = r % 3;
    const float* src = (r < 3 ? w_ih1 : w_hh1) + ((size_t)(G * CC + 4 * g + ww) << 10);
    *(f4*)&wcb[(j << 10) + 4 * tid] = *(const f4*)(src + 4 * tid);
  }
#pragma unroll
  for (int i = 0; i < 4; ++i) {
    h0s[4 * tid + i] = 0.f;
    h1s[4 * tid + i] = 0.f;
  }
  __syncthreads();

  // ---------- skewed recurrence: tick tau -> h0[tau] (A, early) and h1[tau-1] (B/C, late) ----------
  float h0last = 0.f;
  u4 pd0a, pd0b, pd1a, pd1b;  // pend packet loads (4 packets x 8B each pair)
  const float* wr6 = wcb + (w * 6) * 1024;

  for (int tau = 0; tau <= LL; ++tau) {
    PIN12;
    // (1) poll h0 tag tau (parity tau&1); then issue h1 pend
    if (tau > 0) {
      const unsigned ut = (unsigned)tau;
      const unsigned* p0 = ws_u + (tau & 1) * PKT_PAR + 8 * tid;
      vm0();  // pend (issued end of last tick) arrived
      while (pd0a.y != ut || pd0a.w != ut || pd0b.y != ut || pd0b.w != ut) {
        pd0a = ld16v(p0);
        pd0b = ld16v(p0 + 4);
        vm0();
      }
      h0s[4 * tid + 0] = __uint_as_float(pd0a.x);
      h0s[4 * tid + 1] = __uint_as_float(pd0a.z);
      h0s[4 * tid + 2] = __uint_as_float(pd0b.x);
      h0s[4 * tid + 3] = __uint_as_float(pd0b.z);
      const unsigned* p1 = ws_u + H1_BASE + (tau & 1) * PKT_PAR + 8 * tid;
      pd1a = ld16v(p1);
      pd1b = ld16v(p1 + 4);
    }
    __syncthreads();  // S1: h0s ready

    // (2) A-phase: 3 VGPR dots -> h0[tau]; publish immediately
    float h0new = 0.f;
    if (tau < LL) {
      f4 hc0[4];
#pragma unroll
      for (int k = 0; k < 4; ++k) hc0[k] = *(const f4*)&h0s[256 * k + 4 * lane];
      float pA[3];
#pragma unroll
      for (int G = 0; G < 3; ++G) {
        float p = 0.f;
#pragma unroll
        for (int k = 0; k < 4; ++k) p += dot4(Wa[G * 4 + k], hc0[k]);
        pA[G] = p;
      }
#pragma unroll
      for (int off = 32; off; off >>= 1) {
#pragma unroll
        for (int i = 0; i < 3; ++i) pA[i] += __shfl_xor(pA[i], off, 64);
      }
      float h0prev = h0s[eg];
      float r0 = sigm(cgi0[w] + pA[0] + cbh0[w]);
      float z0 = sigm(cgi0[4 + w] + pA[1] + cbh0[4 + w]);
      float n0 = tanh_(cgi0[8 + w] + r0 * (pA[2] + cbh0[8 + w]));
      h0new = (1.f - z0) * n0 + z0 * h0prev;
      if (tau == LL - 1) h0last = h0new;
      if (lane == 0) {
        u2v pk;
        pk.x = __float_as_uint(h0new);
        pk.y = (unsigned)(tau + 1);
        st8u(ws_u + ((tau + 1) & 1) * PKT_PAR + 2 * eg, pk);
      }
    }

    // (3) poll h1 tag tau (parity tau&1) -> h1s
    if (tau > 0) {
      const unsigned ut = (unsigned)tau;
      const unsigned* p1 = ws_u + H1_BASE + (tau & 1) * PKT_PAR + 8 * tid;
      vm0();
      while (pd1a.y != ut || pd1a.w != ut || pd1b.y != ut || pd1b.w != ut) {
        pd1a = ld16v(p1);
        pd1b = ld16v(p1 + 4);
        vm0();
      }
      h1s[4 * tid + 0] = __uint_as_float(pd1a.x);
      h1s[4 * tid + 1] = __uint_as_float(pd1a.z);
      h1s[4 * tid + 2] = __uint_as_float(pd1b.x);
      h1s[4 * tid + 3] = __uint_as_float(pd1b.z);
    }
    __syncthreads();  // S2: h1s ready (h0s reads of A-phase all done too)

    // (4) B/C phase: h1[tau-1] = gru1(h0[tau-1] via C-dots, h1[tau-2] via B-dots)
    if (tau >= 1) {
      f4 hc0[4], hc1[4];
#pragma unroll
      for (int k = 0; k < 4; ++k) {
        hc0[k] = *(const f4*)&h0s[256 * k + 4 * lane];
        hc1[k] = *(const f4*)&h1s[256 * k + 4 * lane];
      }
      float pC[3], pB[3];
#pragma unroll
      for (int G = 0; G < 3; ++G) {
        float pc = 0.f, pb = 0.f;
#pragma unroll
        for (int k = 0; k < 4; ++k) {
          int off = 256 * k + 4 * lane;
          pc += dot4(*(const f4*)&wr6[G * 1024 + off], hc0[k]);
          pb += dot4(*(const f4*)&wr6[(3 + G) * 1024 + off], hc1[k]);
        }
        pC[G] = pc;
        pB[G] = pb;
      }
#pragma unroll
      for (int off = 32; off; off >>= 1) {
#pragma unroll
        for (int i = 0; i < 3; ++i) {
          pC[i] += __shfl_xor(pC[i], off, 64);
          pB[i] += __shfl_xor(pB[i], off, 64);
        }
      }
      float h1prev = h1s[eg];
      float r1 = sigm(pC[0] + cbi1[w] + pB[0] + cbh1[w]);
      float z1 = sigm(pC[1] + cbi1[4 + w] + pB[1] + cbh1[4 + w]);
      float n1 = tanh_(pC[2] + cbi1[8 + w] + r1 * (pB[2] + cbh1[8 + w]));
      float h1new = (1.f - z1) * n1 + z1 * h1prev;
      if (lane == 0) {
        if (tau < LL) {
          u2v pk;
          pk.x = __float_as_uint(h1new);
          pk.y = (unsigned)(tau + 1);
          st8u(ws_u + H1_BASE + ((tau + 1) & 1) * PKT_PAR + 2 * eg, pk);
        }
        out[(size_t)(tau - 1) * CC + eg] = h1new;
        if (tau == LL) {
          out[(size_t)LL * CC + eg] = h0last;
          out[(size_t)LL * CC + CC + eg] = h1new;
        }
      }
    } else if (lane == 0) {
      // tau==0: publish h1[-1] = 0 with tag 1
      u2v pk;
      pk.x = 0u;
      pk.y = 1u;
      st8u(ws_u + H1_BASE + 1 * PKT_PAR + 2 * eg, pk);
    }

    // (5) pend h0 prefetch for next tick
    if (tau < LL) {
      const unsigned* np = ws_u + ((tau + 1) & 1) * PKT_PAR + 8 * tid;
      pd0a = ld16v(np);
      pd0b = ld16v(np + 4);
    }
    __syncthreads();  // S3: protect h0s/h1s from next tick's poll writes
  }
}

extern "C" void kernel_launch(void* const* d_in, const int* in_sizes, int n_in,
                              void* d_out, int out_size, void* d_ws, size_t ws_size,
                              hipStream_t stream) {
  const float* x = (const float*)d_in[0];
  const float* attn_w = (const float*)d_in[1];
  const float* w_ih0 = (const float*)d_in[3];
  const float* w_hh0 = (const float*)d_in[4];
  const float* b_ih0 = (const float*)d_in[5];
  const float* b_hh0 = (const float*)d_in[6];
  const float* w_ih1 = (const float*)d_in[7];
  const float* w_hh1 = (const float*)d_in[8];
  const float* b_ih1 = (const float*)d_in[9];
  const float* b_hh1 = (const float*)d_in[10];
  float* out = (float*)d_out;
  float* ws = (float*)d_ws;

  static int attr_set = 0;
  if (!attr_set) {
    hipFuncSetAttribute((const void*)decoder_kernel,
                        hipFuncAttributeMaxDynamicSharedMemorySize, 24 * 1024 * 4);
    attr_set = 1;
  }

  // zero packet tags + gbar flags every call (tags start at 1 => 0 invalid; no ABA)
  hipMemsetAsync(d_ws, 0, WS_MEMSET_BYTES, stream);

  void* args[] = {&x,     &attn_w, &w_ih0, &w_hh0, &b_ih0, &b_hh0,
                  &w_ih1, &w_hh1,  &b_ih1, &b_hh1, &out,   &ws};
  hipLaunchCooperativeKernel((void*)decoder_kernel, dim3(NWG), dim3(NT), args,
                             24 * 1024 * 4, stream);
}

// Round 10
// 6985.522 us; speedup vs baseline: 1.2185x; 1.0502x over previous
//
#include <hip/hip_runtime.h>
#include <math.h>

#define CC 1024
#define LL 2048
#define NWG 256
#define NT 256

typedef float f4 __attribute__((ext_vector_type(4)));
typedef unsigned u4 __attribute__((ext_vector_type(4)));

// ws word layout:
// [0 .. 4095]     h0 packets: 2 parities x 1024 elems x 2 words (val, tag) [memset 0]
// [4096 .. 8191]  h1 packets: same layout                                  [memset 0]
// [8192..16383]   gbar arrival epochs (256 x 32 words, 128B lines)         [memset 0]
// [16384]         gbar release epoch                                       [memset 0]
// [16448..18495]  logits[2048]
// [18496..19519]  av[1024]
// tag = tau+1 written at tick tau, parity (tau+1)&1; exact-match poll.
// Publish = 64-bit agent-scope atomic exchange (executes at MALL, keeps the
// line cache-resident on-chip; R9's sc0sc1 plain stores streamed to HBM).
#define H1_BASE 4096
#define PKT_PAR 2048
#define WS_FLAGS 8192
#define WS_REL 16384
#define WS_LOGITS 16448
#define WS_AV (WS_LOGITS + LL)
#define WS_MEMSET_BYTES ((WS_REL + 64) * 4)

__device__ __forceinline__ float aload(const float* p) {
  return __hip_atomic_load(p, __ATOMIC_RELAXED, __HIP_MEMORY_SCOPE_AGENT);
}
__device__ __forceinline__ void astore(float* p, float v) {
  __hip_atomic_store(p, v, __ATOMIC_RELAXED, __HIP_MEMORY_SCOPE_AGENT);
}
__device__ __forceinline__ float sigm(float x) { return 1.0f / (1.0f + __expf(-x)); }
__device__ __forceinline__ float tanh_(float x) { return 2.0f / (1.0f + __expf(-2.0f * x)) - 1.0f; }
__device__ __forceinline__ float dot4(f4 a, f4 b) {
  return fmaf(a.x, b.x, fmaf(a.y, b.y, fmaf(a.z, b.z, a.w * b.w)));
}

// L2-bypass poll load (served at the coherence point)
__device__ __forceinline__ u4 ld16v(const unsigned* p) {  // issue only, no wait
  u4 r;
  asm volatile("global_load_dwordx4 %0, %1, off sc0 sc1" : "=v"(r) : "v"(p) : "memory");
  return r;
}
__device__ __forceinline__ void vm0() { asm volatile("s_waitcnt vmcnt(0)" ::: "memory"); }

// publish: 8B (val,tag) via agent-scope atomic swap -> executes at MALL,
// line stays on-chip; old value discarded.
__device__ __forceinline__ void pub8(unsigned* p, unsigned val, unsigned tag) {
  unsigned long long pk = (unsigned long long)val | ((unsigned long long)tag << 32);
  (void)__hip_atomic_exchange((unsigned long long*)p, pk, __ATOMIC_RELAXED,
                              __HIP_MEMORY_SCOPE_AGENT);
}

// prologue-only arrival-slot barrier (relaxed spins + one acquire)
__device__ __forceinline__ void gbar(unsigned* ws_u, unsigned epoch) {
  __syncthreads();
  if (blockIdx.x == 0) {
    const int i = threadIdx.x;
    if (i > 0 && i < NWG) {
      unsigned* slot = ws_u + WS_FLAGS + i * 32;
      while (__hip_atomic_load(slot, __ATOMIC_RELAXED, __HIP_MEMORY_SCOPE_AGENT) < epoch) {
      }
      (void)__hip_atomic_load(slot, __ATOMIC_ACQUIRE, __HIP_MEMORY_SCOPE_AGENT);
    }
    __syncthreads();
    if (i == 0)
      __hip_atomic_store(ws_u + WS_REL, epoch, __ATOMIC_RELEASE, __HIP_MEMORY_SCOPE_AGENT);
    __syncthreads();
  } else {
    if (threadIdx.x == 0) {
      __hip_atomic_store(ws_u + WS_FLAGS + blockIdx.x * 32, epoch, __ATOMIC_RELEASE,
                         __HIP_MEMORY_SCOPE_AGENT);
      unsigned* rel = ws_u + WS_REL;
      while (__hip_atomic_load(rel, __ATOMIC_RELAXED, __HIP_MEMORY_SCOPE_AGENT) < epoch) {
      }
      (void)__hip_atomic_load(rel, __ATOMIC_ACQUIRE, __HIP_MEMORY_SCOPE_AGENT);
    }
    __syncthreads();
  }
}

#define PIN12                                                                        \
  asm volatile("" : "+v"(Wa[0]), "+v"(Wa[1]), "+v"(Wa[2]), "+v"(Wa[3]), "+v"(Wa[4]), \
                    "+v"(Wa[5]), "+v"(Wa[6]), "+v"(Wa[7]), "+v"(Wa[8]), "+v"(Wa[9]), \
                    "+v"(Wa[10]), "+v"(Wa[11]))

__global__ __launch_bounds__(NT, 1) void decoder_kernel(
    const float* __restrict__ x, const float* __restrict__ attn_w,
    const float* __restrict__ w_ih0, const float* __restrict__ w_hh0,
    const float* __restrict__ b_ih0, const float* __restrict__ b_hh0,
    const float* __restrict__ w_ih1, const float* __restrict__ w_hh1,
    const float* __restrict__ b_ih1, const float* __restrict__ b_hh1,
    float* __restrict__ out, float* __restrict__ ws) {
  const int g = blockIdx.x;
  const int tid = threadIdx.x;
  const int lane = tid & 63;
  const int w = tid >> 6;
  const int eg = 4 * g + w;  // element owned by this wave

  unsigned* ws_u = (unsigned*)ws;

  extern __shared__ float wcb[];  // 24 rows x 1024 f32 = 96 KB: wave w rows at (w*6+idx)
                                  // idx 0..2 = W_ih1 gates (C), 3..5 = W_hh1 gates (B)
  __shared__ __align__(16) float h0s[CC];
  __shared__ __align__(16) float h1s[CC];
  __shared__ float cgi0[12], cbh0[12], cbh1[12], cbi1[12];
  __shared__ float red[NT];

  // ---------- P0: logits[t] = dot(w2, x[t]) ----------
  {
    const float* w2 = attn_w + CC;
#pragma unroll
    for (int s = 0; s < 2; ++s) {
      int t = 8 * g + 2 * w + s;
      const float* xr = x + (size_t)t * CC;
      float p = 0.f;
#pragma unroll
      for (int k = 0; k < 4; ++k) {
        f4 xa = *(const f4*)(xr + 256 * k + 4 * lane);
        f4 wa = *(const f4*)(w2 + 256 * k + 4 * lane);
        p += dot4(xa, wa);
      }
#pragma unroll
      for (int off = 32; off; off >>= 1) p += __shfl_xor(p, off, 64);
      if (lane == 0) astore(ws + WS_LOGITS + t, p);
    }
  }
  gbar(ws_u, 1);

  // ---------- P1: softmax over L, av columns [4g,4g+4) ----------
  {
    float myl[8];
#pragma unroll
    for (int s = 0; s < 8; ++s) myl[s] = aload(ws + WS_LOGITS + tid + 256 * s);
    float lm = myl[0];
#pragma unroll
    for (int s = 1; s < 8; ++s) lm = fmaxf(lm, myl[s]);
    red[tid] = lm;
    __syncthreads();
    for (int stp = 128; stp; stp >>= 1) {
      if (tid < stp) red[tid] = fmaxf(red[tid], red[tid + stp]);
      __syncthreads();
    }
    float m = red[0];
    __syncthreads();
    float myw[8];
    float ls = 0.f;
#pragma unroll
    for (int s = 0; s < 8; ++s) {
      myw[s] = __expf(myl[s] - m);
      ls += myw[s];
    }
    red[tid] = ls;
    __syncthreads();
    for (int stp = 128; stp; stp >>= 1) {
      if (tid < stp) red[tid] += red[tid + stp];
      __syncthreads();
    }
    float invZ = 1.0f / red[0];
    __syncthreads();
    float acc[4] = {0.f, 0.f, 0.f, 0.f};
#pragma unroll
    for (int s = 0; s < 8; ++s) {
      int t = tid + 256 * s;
      f4 xa = *(const f4*)(x + (size_t)t * CC + 4 * g);
      acc[0] = fmaf(myw[s], xa.x, acc[0]);
      acc[1] = fmaf(myw[s], xa.y, acc[1]);
      acc[2] = fmaf(myw[s], xa.z, acc[2]);
      acc[3] = fmaf(myw[s], xa.w, acc[3]);
    }
    for (int i = 0; i < 4; ++i) {
      red[tid] = acc[i];
      __syncthreads();
      for (int stp = 128; stp; stp >>= 1) {
        if (tid < stp) red[tid] += red[tid + stp];
        __syncthreads();
      }
      if (tid == 0) astore(ws + WS_AV + 4 * g + i, red[0] * invZ);
      __syncthreads();
    }
  }
  gbar(ws_u, 2);

  // ---------- P2: gi0 = W_ih0 . av + b_ih0 (this WG's 12 rows); biases ----------
#pragma unroll
  for (int i = 0; i < 4; ++i) h0s[4 * tid + i] = aload(ws + WS_AV + 4 * tid + i);
  __syncthreads();
  {
    f4 hc[4];
#pragma unroll
    for (int k = 0; k < 4; ++k) hc[k] = *(const f4*)&h0s[256 * k + 4 * lane];
#pragma unroll
    for (int jj = 0; jj < 3; ++jj) {
      int j = 3 * w + jj;
      int gate = j >> 2, e = j & 3;
      int row = gate * CC + 4 * g + e;
      const float* wr = w_ih0 + (size_t)row * CC;
      float p = 0.f;
#pragma unroll
      for (int k = 0; k < 4; ++k) p += dot4(*(const f4*)(wr + 256 * k + 4 * lane), hc[k]);
#pragma unroll
      for (int off = 32; off; off >>= 1) p += __shfl_xor(p, off, 64);
      if (lane == 0) cgi0[j] = p + b_ih0[row];
    }
  }
  if (tid < 12) {
    int gate = tid >> 2, e = tid & 3;
    int row = gate * CC + 4 * g + e;
    cbh0[tid] = b_hh0[row];
    cbh1[tid] = b_hh1[row];
    cbi1[tid] = b_ih1[row];
  }

  // ---------- A-weights (W_hh0, 3 gate rows of eg) -> VGPRs (48 regs, pinned) ----------
  f4 Wa[12];
#pragma unroll
  for (int G = 0; G < 3; ++G) {
    const float* wr = w_hh0 + ((size_t)(G * CC + eg) << 10);
#pragma unroll
    for (int k = 0; k < 4; ++k) Wa[G * 4 + k] = *(const f4*)(wr + 256 * k + 4 * lane);
  }

  // ---------- B/C weights -> LDS ----------
#pragma unroll
  for (int j = 0; j < 24; ++j) {
    int ww = j / 6, r = j % 6;
    int G = r % 3;
    const float* src = (r < 3 ? w_ih1 : w_hh1) + ((size_t)(G * CC + 4 * g + ww) << 10);
    *(f4*)&wcb[(j << 10) + 4 * tid] = *(const f4*)(src + 4 * tid);
  }
#pragma unroll
  for (int i = 0; i < 4; ++i) {
    h0s[4 * tid + i] = 0.f;
    h1s[4 * tid + i] = 0.f;
  }
  __syncthreads();

  // ---------- skewed recurrence: tick tau -> h0[tau] (A, early) and h1[tau-1] (B/C, late) ----------
  float h0last = 0.f;
  u4 pd0a, pd0b, pd1a, pd1b;  // pend packet loads (4 packets x 8B each pair)
  const float* wr6 = wcb + (w * 6) * 1024;

  for (int tau = 0; tau <= LL; ++tau) {
    PIN12;
    // (1) poll h0 tag tau (parity tau&1); then issue h1 pend
    if (tau > 0) {
      const unsigned ut = (unsigned)tau;
      const unsigned* p0 = ws_u + (tau & 1) * PKT_PAR + 8 * tid;
      vm0();  // pend (issued end of last tick) arrived
      while (pd0a.y != ut || pd0a.w != ut || pd0b.y != ut || pd0b.w != ut) {
        pd0a = ld16v(p0);
        pd0b = ld16v(p0 + 4);
        vm0();
      }
      h0s[4 * tid + 0] = __uint_as_float(pd0a.x);
      h0s[4 * tid + 1] = __uint_as_float(pd0a.z);
      h0s[4 * tid + 2] = __uint_as_float(pd0b.x);
      h0s[4 * tid + 3] = __uint_as_float(pd0b.z);
      const unsigned* p1 = ws_u + H1_BASE + (tau & 1) * PKT_PAR + 8 * tid;
      pd1a = ld16v(p1);
      pd1b = ld16v(p1 + 4);
    }
    __syncthreads();  // S1: h0s ready

    // (2) A-phase: 3 VGPR dots -> h0[tau]; publish immediately
    float h0new = 0.f;
    if (tau < LL) {
      f4 hc0[4];
#pragma unroll
      for (int k = 0; k < 4; ++k) hc0[k] = *(const f4*)&h0s[256 * k + 4 * lane];
      float pA[3];
#pragma unroll
      for (int G = 0; G < 3; ++G) {
        float p = 0.f;
#pragma unroll
        for (int k = 0; k < 4; ++k) p += dot4(Wa[G * 4 + k], hc0[k]);
        pA[G] = p;
      }
#pragma unroll
      for (int off = 32; off; off >>= 1) {
#pragma unroll
        for (int i = 0; i < 3; ++i) pA[i] += __shfl_xor(pA[i], off, 64);
      }
      float h0prev = h0s[eg];
      float r0 = sigm(cgi0[w] + pA[0] + cbh0[w]);
      float z0 = sigm(cgi0[4 + w] + pA[1] + cbh0[4 + w]);
      float n0 = tanh_(cgi0[8 + w] + r0 * (pA[2] + cbh0[8 + w]));
      h0new = (1.f - z0) * n0 + z0 * h0prev;
      if (tau == LL - 1) h0last = h0new;
      if (lane == 0)
        pub8(ws_u + ((tau + 1) & 1) * PKT_PAR + 2 * eg, __float_as_uint(h0new),
             (unsigned)(tau + 1));
    }

    // (3) poll h1 tag tau (parity tau&1) -> h1s
    if (tau > 0) {
      const unsigned ut = (unsigned)tau;
      const unsigned* p1 = ws_u + H1_BASE + (tau & 1) * PKT_PAR + 8 * tid;
      vm0();
      while (pd1a.y != ut || pd1a.w != ut || pd1b.y != ut || pd1b.w != ut) {
        pd1a = ld16v(p1);
        pd1b = ld16v(p1 + 4);
        vm0();
      }
      h1s[4 * tid + 0] = __uint_as_float(pd1a.x);
      h1s[4 * tid + 1] = __uint_as_float(pd1a.z);
      h1s[4 * tid + 2] = __uint_as_float(pd1b.x);
      h1s[4 * tid + 3] = __uint_as_float(pd1b.z);
    }
    __syncthreads();  // S2: h1s ready (h0s reads of A-phase all done too)

    // (4) B/C phase: h1[tau-1] = gru1(h0[tau-1] via C-dots, h1[tau-2] via B-dots)
    if (tau >= 1) {
      f4 hc0[4], hc1[4];
#pragma unroll
      for (int k = 0; k < 4; ++k) {
        hc0[k] = *(const f4*)&h0s[256 * k + 4 * lane];
        hc1[k] = *(const f4*)&h1s[256 * k + 4 * lane];
      }
      float pC[3], pB[3];
#pragma unroll
      for (int G = 0; G < 3; ++G) {
        float pc = 0.f, pb = 0.f;
#pragma unroll
        for (int k = 0; k < 4; ++k) {
          int off = 256 * k + 4 * lane;
          pc += dot4(*(const f4*)&wr6[G * 1024 + off], hc0[k]);
          pb += dot4(*(const f4*)&wr6[(3 + G) * 1024 + off], hc1[k]);
        }
        pC[G] = pc;
        pB[G] = pb;
      }
#pragma unroll
      for (int off = 32; off; off >>= 1) {
#pragma unroll
        for (int i = 0; i < 3; ++i) {
          pC[i] += __shfl_xor(pC[i], off, 64);
          pB[i] += __shfl_xor(pB[i], off, 64);
        }
      }
      float h1prev = h1s[eg];
      float r1 = sigm(pC[0] + cbi1[w] + pB[0] + cbh1[w]);
      float z1 = sigm(pC[1] + cbi1[4 + w] + pB[1] + cbh1[4 + w]);
      float n1 = tanh_(pC[2] + cbi1[8 + w] + r1 * (pB[2] + cbh1[8 + w]));
      float h1new = (1.f - z1) * n1 + z1 * h1prev;
      if (lane == 0) {
        if (tau < LL)
          pub8(ws_u + H1_BASE + ((tau + 1) & 1) * PKT_PAR + 2 * eg,
               __float_as_uint(h1new), (unsigned)(tau + 1));
        out[(size_t)(tau - 1) * CC + eg] = h1new;
        if (tau == LL) {
          out[(size_t)LL * CC + eg] = h0last;
          out[(size_t)LL * CC + CC + eg] = h1new;
        }
      }
    } else if (lane == 0) {
      // tau==0: publish h1[-1] = 0 with tag 1
      pub8(ws_u + H1_BASE + 1 * PKT_PAR + 2 * eg, 0u, 1u);
    }

    // (5) pend h0 prefetch for next tick
    if (tau < LL) {
      const unsigned* np = ws_u + ((tau + 1) & 1) * PKT_PAR + 8 * tid;
      pd0a = ld16v(np);
      pd0b = ld16v(np + 4);
    }
    __syncthreads();  // S3: protect h0s/h1s from next tick's poll writes
  }
}

extern "C" void kernel_launch(void* const* d_in, const int* in_sizes, int n_in,
                              void* d_out, int out_size, void* d_ws, size_t ws_size,
                              hipStream_t stream) {
  const float* x = (const float*)d_in[0];
  const float* attn_w = (const float*)d_in[1];
  const float* w_ih0 = (const float*)d_in[3];
  const float* w_hh0 = (const float*)d_in[4];
  const float* b_ih0 = (const float*)d_in[5];
  const float* b_hh0 = (const float*)d_in[6];
  const float* w_ih1 = (const float*)d_in[7];
  const float* w_hh1 = (const float*)d_in[8];
  const float* b_ih1 = (const float*)d_in[9];
  const float* b_hh1 = (const float*)d_in[10];
  float* out = (float*)d_out;
  float* ws = (float*)d_ws;

  static int attr_set = 0;
  if (!attr_set) {
    hipFuncSetAttribute((const void*)decoder_kernel,
                        hipFuncAttributeMaxDynamicSharedMemorySize, 24 * 1024 * 4);
    attr_set = 1;
  }

  // zero packet tags + gbar flags every call (tags start at 1 => 0 invalid; no ABA)
  hipMemsetAsync(d_ws, 0, WS_MEMSET_BYTES, stream);

  void* args[] = {&x,     &attn_w, &w_ih0, &w_hh0, &b_ih0, &b_hh0,
                  &w_ih1, &w_hh1,  &b_ih1, &b_hh1, &out,   &ws};
  hipLaunchCooperativeKernel((void*)decoder_kernel, dim3(NWG), dim3(NT), args,
                             24 * 1024 * 4, stream);
}